// Round 1
// baseline (1049.976 us; speedup 1.0000x reference)
//
#include <hip/hip_runtime.h>
#include <hip/hip_bf16.h>

// PAM (position attention): B=8, C=512, mid=64, N=64*64=4096.
// out = gamma * (V @ softmax(Q K^T)^T) + x, all projections 1x1 convs.
// Strategy: exact-fp32 Q/K projections -> bf16 hi/lo split -> 3-term MFMA QK^T
// (fp32-accurate logits); single-bf16 V path (error ~5e-3 << 0.115 threshold).
// Flash-style attention, S never materialized in HBM.

#define BB 8
#define CC 512
#define MM 64
#define NN 4096

typedef __attribute__((ext_vector_type(8))) short bf16x8;
typedef __attribute__((ext_vector_type(4))) float f32x4;

__device__ __forceinline__ unsigned short f2bf(float f) {
  union { float f; unsigned u; } v; v.f = f;
  unsigned r = v.u + 0x7fffu + ((v.u >> 16) & 1u);  // RNE
  return (unsigned short)(r >> 16);
}
__device__ __forceinline__ float bf2f(unsigned short h) {
  union { unsigned u; float f; } v; v.u = ((unsigned)h) << 16;
  return v.f;
}

// ---------------- kernel 1: x [B][C][N] f32 -> xT [B][N][C] bf16 ----------------
__global__ __launch_bounds__(256) void k_transpose(const float* __restrict__ x,
                                                   unsigned short* __restrict__ xT) {
  __shared__ float tile[64][65];  // stride 65: conflict-free both directions
  const int b = blockIdx.z, c0 = blockIdx.y * 64, n0 = blockIdx.x * 64;
  const int t = threadIdx.x;
  {
    const int nl = t & 63, cl0 = t >> 6;
    const float* xp = x + ((size_t)b * CC + c0) * NN + n0;
#pragma unroll
    for (int r = 0; r < 16; r++) {
      const int cl = cl0 + r * 4;
      tile[cl][nl] = xp[(size_t)cl * NN + nl];
    }
  }
  __syncthreads();
  {
    const int cl = t & 63, nl0 = t >> 6;
    unsigned short* xtp = xT + ((size_t)b * NN + n0) * CC + c0;
#pragma unroll
    for (int r = 0; r < 16; r++) {
      const int nl = nl0 + r * 4;
      xtp[(size_t)nl * CC + cl] = f2bf(tile[cl][nl]);
    }
  }
}

// ------------- kernel 2: exact fp32 Q/K projection + hi/lo bf16 split -------------
// qT[b][n][m] = sum_c wq[m][c] x[b][c][n] + bq[m]; stored as hi+lo bf16.
__global__ __launch_bounds__(256) void k_qkproj(
    const float* __restrict__ x, const float* __restrict__ wq, const float* __restrict__ bq,
    const float* __restrict__ wk, const float* __restrict__ bk,
    unsigned short* __restrict__ qhi, unsigned short* __restrict__ qlo,
    unsigned short* __restrict__ khi, unsigned short* __restrict__ klo) {
  __shared__ float xs[64][68];   // [c][n] stride 68: float4-aligned reads
  __shared__ float wqs[64][65];  // [m][c] stride 65: broadcast column reads
  __shared__ float wks[64][65];
  const int b = blockIdx.y, n0 = blockIdx.x * 64;
  const int t = threadIdx.x;
  const int m4 = (t & 15) * 4, n4 = (t >> 4) * 4;
  const int cl = t & 63, r0 = t >> 6;
  float qa[4][4] = {}, ka[4][4] = {};
  for (int c0 = 0; c0 < CC; c0 += 64) {
    __syncthreads();
#pragma unroll
    for (int r = 0; r < 16; r++) {
      const int row = r0 + r * 4;
      xs[row][cl] = x[((size_t)b * CC + c0 + row) * NN + n0 + cl];
      wqs[row][cl] = wq[(size_t)row * CC + c0 + cl];
      wks[row][cl] = wk[(size_t)row * CC + c0 + cl];
    }
    __syncthreads();
#pragma unroll 8
    for (int cc = 0; cc < 64; cc++) {
      const f32x4 xv = *reinterpret_cast<const f32x4*>(&xs[cc][n4]);
#pragma unroll
      for (int mi = 0; mi < 4; mi++) {
        const float wqv = wqs[m4 + mi][cc];
        const float wkv = wks[m4 + mi][cc];
#pragma unroll
        for (int ni = 0; ni < 4; ni++) {
          qa[mi][ni] += wqv * xv[ni];
          ka[mi][ni] += wkv * xv[ni];
        }
      }
    }
  }
#pragma unroll
  for (int ni = 0; ni < 4; ni++) {
    const int n = n0 + n4 + ni;
    const size_t base = ((size_t)b * NN + n) * MM + m4;
    unsigned short qh[4], qlo_[4], kh[4], klo_[4];
#pragma unroll
    for (int mi = 0; mi < 4; mi++) {
      const float qv = qa[mi][ni] + bq[m4 + mi];
      const unsigned short h = f2bf(qv);
      qh[mi] = h; qlo_[mi] = f2bf(qv - bf2f(h));
      const float kv = ka[mi][ni] + bk[m4 + mi];
      const unsigned short h2 = f2bf(kv);
      kh[mi] = h2; klo_[mi] = f2bf(kv - bf2f(h2));
    }
    *reinterpret_cast<ushort4*>(qhi + base) = make_ushort4(qh[0], qh[1], qh[2], qh[3]);
    *reinterpret_cast<ushort4*>(qlo + base) = make_ushort4(qlo_[0], qlo_[1], qlo_[2], qlo_[3]);
    *reinterpret_cast<ushort4*>(khi + base) = make_ushort4(kh[0], kh[1], kh[2], kh[3]);
    *reinterpret_cast<ushort4*>(klo + base) = make_ushort4(klo_[0], klo_[1], klo_[2], klo_[3]);
  }
}

// ---------------- kernel 3: V projection (bf16 MFMA) -> v [B][C][N] bf16 ----------------
__global__ __launch_bounds__(256) void k_vproj(
    const unsigned short* __restrict__ xT, const float* __restrict__ wv,
    const float* __restrict__ bv, unsigned short* __restrict__ vbf) {
  const int b = blockIdx.z, c0 = blockIdx.y * 64, n0 = blockIdx.x * 128;
  const int t = threadIdx.x, w = t >> 6, l = t & 63, lr = l & 15, g = l >> 4;
  const int nbase = n0 + w * 32;
  f32x4 acc[4][2] = {};
  for (int ks = 0; ks < 16; ks++) {
    const int kk = ks * 32 + g * 8;
    bf16x8 bfr[2];
#pragma unroll
    for (int nf = 0; nf < 2; nf++) {
      const int n = nbase + nf * 16 + lr;
      bfr[nf] = *reinterpret_cast<const bf16x8*>(xT + ((size_t)b * NN + n) * CC + kk);
    }
#pragma unroll
    for (int cf = 0; cf < 4; cf++) {
      const int c = c0 + cf * 16 + lr;
      const float* wp = wv + (size_t)c * CC + kk;
      const f32x4 w0 = *reinterpret_cast<const f32x4*>(wp);
      const f32x4 w1 = *reinterpret_cast<const f32x4*>(wp + 4);
      bf16x8 af;
      af[0] = (short)f2bf(w0[0]); af[1] = (short)f2bf(w0[1]);
      af[2] = (short)f2bf(w0[2]); af[3] = (short)f2bf(w0[3]);
      af[4] = (short)f2bf(w1[0]); af[5] = (short)f2bf(w1[1]);
      af[6] = (short)f2bf(w1[2]); af[7] = (short)f2bf(w1[3]);
      acc[cf][0] = __builtin_amdgcn_mfma_f32_16x16x32_bf16(af, bfr[0], acc[cf][0], 0, 0, 0);
      acc[cf][1] = __builtin_amdgcn_mfma_f32_16x16x32_bf16(af, bfr[1], acc[cf][1], 0, 0, 0);
    }
  }
#pragma unroll
  for (int cf = 0; cf < 4; cf++) {
#pragma unroll
    for (int r = 0; r < 4; r++) {
      const int c = c0 + cf * 16 + g * 4 + r;
      const float bvv = bv[c];
#pragma unroll
      for (int nf = 0; nf < 2; nf++) {
        const int n = nbase + nf * 16 + lr;
        vbf[((size_t)b * CC + c) * NN + n] = f2bf(acc[cf][nf][r] + bvv);
      }
    }
  }
}

// ---------------- kernel 4: flash attention + residual ----------------
// Block: 256 thr (4 waves), I_TILE=32 queries, J_TILE=64 keys/iter.
// Wave w owns O strip [32 i][128 c] (c base = w*128). S^T via 3-term split MFMA.
__global__ __launch_bounds__(256) void k_attn(
    const unsigned short* __restrict__ qhi, const unsigned short* __restrict__ qlo,
    const unsigned short* __restrict__ khi, const unsigned short* __restrict__ klo,
    const unsigned short* __restrict__ vbf, const float* __restrict__ x,
    const float* __restrict__ gamma, float* __restrict__ out) {
  __shared__ float S_lds[32][68];           // [i][j], stride 68 f32 (aligned, 2-way max)
  __shared__ unsigned short P_lds[32][72];  // [i][j] bf16, stride 72 (144B rows)
  // batch-pinned XCD swizzle: 8 batches <-> 8 XCDs so each L2 holds one batch's K/V
  const int b = blockIdx.x & 7;
  const int i0 = (blockIdx.x >> 3) * 32;
  const int t = threadIdx.x, w = t >> 6, l = t & 63, lr = l & 15, g = l >> 4;
  const int if_ = w >> 1, jf0 = (w & 1) * 2;

  // hoist this wave's Q B-fragments (i = i0 + if_*16 + lr)
  bf16x8 qhF[2], qlF[2];
  {
    const int i = i0 + if_ * 16 + lr;
#pragma unroll
    for (int ks = 0; ks < 2; ks++) {
      const size_t off = ((size_t)b * NN + i) * MM + ks * 32 + g * 8;
      qhF[ks] = *reinterpret_cast<const bf16x8*>(qhi + off);
      qlF[ks] = *reinterpret_cast<const bf16x8*>(qlo + off);
    }
  }

  f32x4 acc[8][2];
#pragma unroll
  for (int cf = 0; cf < 8; cf++) {
    acc[cf][0] = f32x4{0.f, 0.f, 0.f, 0.f};
    acc[cf][1] = f32x4{0.f, 0.f, 0.f, 0.f};
  }
  float m_run[2] = {-1e30f, -1e30f};
  float s_run[2] = {0.f, 0.f};

  for (int jb = 0; jb < NN; jb += 64) {
    // ---- S^T fragments: this wave covers rows j in [jf0*16, jf0*16+32), cols i half if_
#pragma unroll
    for (int jj = 0; jj < 2; jj++) {
      const int j = jb + (jf0 + jj) * 16 + lr;
      f32x4 sa = f32x4{0.f, 0.f, 0.f, 0.f};
#pragma unroll
      for (int ks = 0; ks < 2; ks++) {
        const size_t off = ((size_t)b * NN + j) * MM + ks * 32 + g * 8;
        const bf16x8 kh = *reinterpret_cast<const bf16x8*>(khi + off);
        const bf16x8 kl = *reinterpret_cast<const bf16x8*>(klo + off);
        sa = __builtin_amdgcn_mfma_f32_16x16x32_bf16(kh, qhF[ks], sa, 0, 0, 0);
        sa = __builtin_amdgcn_mfma_f32_16x16x32_bf16(kh, qlF[ks], sa, 0, 0, 0);
        sa = __builtin_amdgcn_mfma_f32_16x16x32_bf16(kl, qhF[ks], sa, 0, 0, 0);
      }
      // D layout: col i = lr, rows j = g*4 + r (within 16-frag)
      *reinterpret_cast<f32x4*>(&S_lds[if_ * 16 + lr][(jf0 + jj) * 16 + g * 4]) = sa;
    }
    __syncthreads();

    // ---- online softmax stats (each wave redundantly; lane covers j = g*16..g*16+15)
    float scale[2];
#pragma unroll
    for (int tt = 0; tt < 2; tt++) {
      const int il = tt * 16 + lr;
      const f32x4 s0 = *reinterpret_cast<const f32x4*>(&S_lds[il][g * 16]);
      const f32x4 s1 = *reinterpret_cast<const f32x4*>(&S_lds[il][g * 16 + 4]);
      const f32x4 s2 = *reinterpret_cast<const f32x4*>(&S_lds[il][g * 16 + 8]);
      const f32x4 s3 = *reinterpret_cast<const f32x4*>(&S_lds[il][g * 16 + 12]);
      float tm = fmaxf(fmaxf(fmaxf(s0[0], s0[1]), fmaxf(s0[2], s0[3])),
                       fmaxf(fmaxf(s1[0], s1[1]), fmaxf(s1[2], s1[3])));
      tm = fmaxf(tm, fmaxf(fmaxf(fmaxf(s2[0], s2[1]), fmaxf(s2[2], s2[3])),
                           fmaxf(fmaxf(s3[0], s3[1]), fmaxf(s3[2], s3[3]))));
      tm = fmaxf(tm, __shfl_xor(tm, 16));
      tm = fmaxf(tm, __shfl_xor(tm, 32));
      const float mn = fmaxf(m_run[tt], tm);
      const float sc = __expf(m_run[tt] - mn);
      scale[tt] = sc;
      m_run[tt] = mn;
      float p[16];
      p[0] = __expf(s0[0] - mn); p[1] = __expf(s0[1] - mn);
      p[2] = __expf(s0[2] - mn); p[3] = __expf(s0[3] - mn);
      p[4] = __expf(s1[0] - mn); p[5] = __expf(s1[1] - mn);
      p[6] = __expf(s1[2] - mn); p[7] = __expf(s1[3] - mn);
      p[8] = __expf(s2[0] - mn); p[9] = __expf(s2[1] - mn);
      p[10] = __expf(s2[2] - mn); p[11] = __expf(s2[3] - mn);
      p[12] = __expf(s3[0] - mn); p[13] = __expf(s3[1] - mn);
      p[14] = __expf(s3[2] - mn); p[15] = __expf(s3[3] - mn);
      float ps = 0.f;
#pragma unroll
      for (int e = 0; e < 16; e++) ps += p[e];
      ps += __shfl_xor(ps, 16);
      ps += __shfl_xor(ps, 32);
      s_run[tt] = s_run[tt] * sc + ps;
      if (w == 0) {
        bf16x8 p0, p1;
#pragma unroll
        for (int e = 0; e < 8; e++) {
          p0[e] = (short)f2bf(p[e]);
          p1[e] = (short)f2bf(p[e + 8]);
        }
        *reinterpret_cast<bf16x8*>(&P_lds[il][g * 16]) = p0;
        *reinterpret_cast<bf16x8*>(&P_lds[il][g * 16 + 8]) = p1;
      }
    }
    __syncthreads();

    // ---- rescale O, then PV accumulate
#pragma unroll
    for (int cf = 0; cf < 8; cf++) {
      acc[cf][0] *= scale[0];
      acc[cf][1] *= scale[1];
    }
#pragma unroll
    for (int ks = 0; ks < 2; ks++) {
      const bf16x8 pf0 = *reinterpret_cast<const bf16x8*>(&P_lds[lr][ks * 32 + g * 8]);
      const bf16x8 pf1 = *reinterpret_cast<const bf16x8*>(&P_lds[16 + lr][ks * 32 + g * 8]);
#pragma unroll
      for (int cf = 0; cf < 8; cf++) {
        const int c = w * 128 + cf * 16 + lr;
        const bf16x8 vf = *reinterpret_cast<const bf16x8*>(
            vbf + ((size_t)b * CC + c) * NN + jb + ks * 32 + g * 8);
        acc[cf][0] = __builtin_amdgcn_mfma_f32_16x16x32_bf16(vf, pf0, acc[cf][0], 0, 0, 0);
        acc[cf][1] = __builtin_amdgcn_mfma_f32_16x16x32_bf16(vf, pf1, acc[cf][1], 0, 0, 0);
      }
    }
  }

  // ---- epilogue: out = gamma * O/s + x
  const float gm = gamma[0];
  const float inv0 = gm / s_run[0], inv1 = gm / s_run[1];
#pragma unroll
  for (int cf = 0; cf < 8; cf++) {
#pragma unroll
    for (int r = 0; r < 4; r++) {
      const int c = w * 128 + cf * 16 + g * 4 + r;
      const size_t rowo = ((size_t)b * CC + c) * NN;
      const int ia = i0 + lr;
      const int ib2 = i0 + 16 + lr;
      out[rowo + ia] = acc[cf][0][r] * inv0 + x[rowo + ia];
      out[rowo + ib2] = acc[cf][1][r] * inv1 + x[rowo + ib2];
    }
  }
}

extern "C" void kernel_launch(void* const* d_in, const int* in_sizes, int n_in,
                              void* d_out, int out_size, void* d_ws, size_t ws_size,
                              hipStream_t stream) {
  const float* x = (const float*)d_in[0];
  const float* wq = (const float*)d_in[1];
  const float* bq = (const float*)d_in[2];
  const float* wk = (const float*)d_in[3];
  const float* bk = (const float*)d_in[4];
  const float* wv = (const float*)d_in[5];
  const float* bv = (const float*)d_in[6];
  const float* gamma = (const float*)d_in[7];
  float* out = (float*)d_out;

  // workspace layout (80 MB total)
  char* ws = (char*)d_ws;
  unsigned short* xT = (unsigned short*)(ws);               // 32 MB  [B][N][C] bf16
  unsigned short* vbf = (unsigned short*)(ws + 33554432);   // 32 MB  [B][C][N] bf16
  unsigned short* qhi = (unsigned short*)(ws + 67108864);   // 4 MB   [B][N][64] bf16
  unsigned short* qlo = (unsigned short*)(ws + 71303168);   // 4 MB
  unsigned short* khi = (unsigned short*)(ws + 75497472);   // 4 MB
  unsigned short* klo = (unsigned short*)(ws + 79691776);   // 4 MB

  k_transpose<<<dim3(64, 8, 8), 256, 0, stream>>>(x, xT);
  k_qkproj<<<dim3(64, 8), 256, 0, stream>>>(x, wq, bq, wk, bk, qhi, qlo, khi, klo);
  k_vproj<<<dim3(32, 8, 8), 256, 0, stream>>>(xT, wv, bv, vbf);
  k_attn<<<dim3(1024), 256, 0, stream>>>(qhi, qlo, khi, klo, vbf, x, gamma, out);
}

// Round 2
// 934.211 us; speedup vs baseline: 1.1239x; 1.1239x over previous
//
#include <hip/hip_runtime.h>
#include <hip/hip_bf16.h>

// PAM (position attention): B=8, C=512, mid=64, N=64*64=4096.
// out = gamma * (V @ softmax(Q K^T)^T) + x, all projections 1x1 convs.
// Round 2: k_attn restructured — JT=128 (half the barriers), softmax split
// across waves (wave w owns rows 8w..8w+8, no redundant exp), skip-rescale
// when running max unchanged. Numerics identical to round 1 (hi/lo QK split).

#define BB 8
#define CC 512
#define MM 64
#define NN 4096

typedef __attribute__((ext_vector_type(8))) short bf16x8;
typedef __attribute__((ext_vector_type(4))) float f32x4;

__device__ __forceinline__ unsigned short f2bf(float f) {
  union { float f; unsigned u; } v; v.f = f;
  unsigned r = v.u + 0x7fffu + ((v.u >> 16) & 1u);  // RNE
  return (unsigned short)(r >> 16);
}
__device__ __forceinline__ float bf2f(unsigned short h) {
  union { unsigned u; float f; } v; v.u = ((unsigned)h) << 16;
  return v.f;
}

// ---------------- kernel 1: x [B][C][N] f32 -> xT [B][N][C] bf16 ----------------
__global__ __launch_bounds__(256) void k_transpose(const float* __restrict__ x,
                                                   unsigned short* __restrict__ xT) {
  __shared__ float tile[64][65];
  const int b = blockIdx.z, c0 = blockIdx.y * 64, n0 = blockIdx.x * 64;
  const int t = threadIdx.x;
  {
    const int nl = t & 63, cl0 = t >> 6;
    const float* xp = x + ((size_t)b * CC + c0) * NN + n0;
#pragma unroll
    for (int r = 0; r < 16; r++) {
      const int cl = cl0 + r * 4;
      tile[cl][nl] = xp[(size_t)cl * NN + nl];
    }
  }
  __syncthreads();
  {
    const int cl = t & 63, nl0 = t >> 6;
    unsigned short* xtp = xT + ((size_t)b * NN + n0) * CC + c0;
#pragma unroll
    for (int r = 0; r < 16; r++) {
      const int nl = nl0 + r * 4;
      xtp[(size_t)nl * CC + cl] = f2bf(tile[cl][nl]);
    }
  }
}

// ------------- kernel 2: exact fp32 Q/K projection + hi/lo bf16 split -------------
__global__ __launch_bounds__(256) void k_qkproj(
    const float* __restrict__ x, const float* __restrict__ wq, const float* __restrict__ bq,
    const float* __restrict__ wk, const float* __restrict__ bk,
    unsigned short* __restrict__ qhi, unsigned short* __restrict__ qlo,
    unsigned short* __restrict__ khi, unsigned short* __restrict__ klo) {
  __shared__ float xs[64][68];
  __shared__ float wqs[64][65];
  __shared__ float wks[64][65];
  const int b = blockIdx.y, n0 = blockIdx.x * 64;
  const int t = threadIdx.x;
  const int m4 = (t & 15) * 4, n4 = (t >> 4) * 4;
  const int cl = t & 63, r0 = t >> 6;
  float qa[4][4] = {}, ka[4][4] = {};
  for (int c0 = 0; c0 < CC; c0 += 64) {
    __syncthreads();
#pragma unroll
    for (int r = 0; r < 16; r++) {
      const int row = r0 + r * 4;
      xs[row][cl] = x[((size_t)b * CC + c0 + row) * NN + n0 + cl];
      wqs[row][cl] = wq[(size_t)row * CC + c0 + cl];
      wks[row][cl] = wk[(size_t)row * CC + c0 + cl];
    }
    __syncthreads();
#pragma unroll 8
    for (int cc = 0; cc < 64; cc++) {
      const f32x4 xv = *reinterpret_cast<const f32x4*>(&xs[cc][n4]);
#pragma unroll
      for (int mi = 0; mi < 4; mi++) {
        const float wqv = wqs[m4 + mi][cc];
        const float wkv = wks[m4 + mi][cc];
#pragma unroll
        for (int ni = 0; ni < 4; ni++) {
          qa[mi][ni] += wqv * xv[ni];
          ka[mi][ni] += wkv * xv[ni];
        }
      }
    }
  }
#pragma unroll
  for (int ni = 0; ni < 4; ni++) {
    const int n = n0 + n4 + ni;
    const size_t base = ((size_t)b * NN + n) * MM + m4;
    unsigned short qh[4], qlo_[4], kh[4], klo_[4];
#pragma unroll
    for (int mi = 0; mi < 4; mi++) {
      const float qv = qa[mi][ni] + bq[m4 + mi];
      const unsigned short h = f2bf(qv);
      qh[mi] = h; qlo_[mi] = f2bf(qv - bf2f(h));
      const float kv = ka[mi][ni] + bk[m4 + mi];
      const unsigned short h2 = f2bf(kv);
      kh[mi] = h2; klo_[mi] = f2bf(kv - bf2f(h2));
    }
    *reinterpret_cast<ushort4*>(qhi + base) = make_ushort4(qh[0], qh[1], qh[2], qh[3]);
    *reinterpret_cast<ushort4*>(qlo + base) = make_ushort4(qlo_[0], qlo_[1], qlo_[2], qlo_[3]);
    *reinterpret_cast<ushort4*>(khi + base) = make_ushort4(kh[0], kh[1], kh[2], kh[3]);
    *reinterpret_cast<ushort4*>(klo + base) = make_ushort4(klo_[0], klo_[1], klo_[2], klo_[3]);
  }
}

// ---------------- kernel 3: V projection (bf16 MFMA) -> v [B][C][N] bf16 ----------------
__global__ __launch_bounds__(256) void k_vproj(
    const unsigned short* __restrict__ xT, const float* __restrict__ wv,
    const float* __restrict__ bv, unsigned short* __restrict__ vbf) {
  const int b = blockIdx.z, c0 = blockIdx.y * 64, n0 = blockIdx.x * 128;
  const int t = threadIdx.x, w = t >> 6, l = t & 63, lr = l & 15, g = l >> 4;
  const int nbase = n0 + w * 32;
  f32x4 acc[4][2] = {};
  for (int ks = 0; ks < 16; ks++) {
    const int kk = ks * 32 + g * 8;
    bf16x8 bfr[2];
#pragma unroll
    for (int nf = 0; nf < 2; nf++) {
      const int n = nbase + nf * 16 + lr;
      bfr[nf] = *reinterpret_cast<const bf16x8*>(xT + ((size_t)b * NN + n) * CC + kk);
    }
#pragma unroll
    for (int cf = 0; cf < 4; cf++) {
      const int c = c0 + cf * 16 + lr;
      const float* wp = wv + (size_t)c * CC + kk;
      const f32x4 w0 = *reinterpret_cast<const f32x4*>(wp);
      const f32x4 w1 = *reinterpret_cast<const f32x4*>(wp + 4);
      bf16x8 af;
      af[0] = (short)f2bf(w0[0]); af[1] = (short)f2bf(w0[1]);
      af[2] = (short)f2bf(w0[2]); af[3] = (short)f2bf(w0[3]);
      af[4] = (short)f2bf(w1[0]); af[5] = (short)f2bf(w1[1]);
      af[6] = (short)f2bf(w1[2]); af[7] = (short)f2bf(w1[3]);
      acc[cf][0] = __builtin_amdgcn_mfma_f32_16x16x32_bf16(af, bfr[0], acc[cf][0], 0, 0, 0);
      acc[cf][1] = __builtin_amdgcn_mfma_f32_16x16x32_bf16(af, bfr[1], acc[cf][1], 0, 0, 0);
    }
  }
#pragma unroll
  for (int cf = 0; cf < 4; cf++) {
#pragma unroll
    for (int r = 0; r < 4; r++) {
      const int c = c0 + cf * 16 + g * 4 + r;
      const float bvv = bv[c];
#pragma unroll
      for (int nf = 0; nf < 2; nf++) {
        const int n = nbase + nf * 16 + lr;
        vbf[((size_t)b * CC + c) * NN + n] = f2bf(acc[cf][nf][r] + bvv);
      }
    }
  }
}

// ---------------- kernel 4: flash attention + residual ----------------
// 4 waves, I_TILE=32, JT=128. QK: wave w computes S^T frags (if_=w>>1, jf0=(w&1)*4).
// Softmax: wave w owns rows [8w,8w+8) — lane handles 16 entries, shfl_xor(8/16/32)
// row-reduce, running (m,s) in owner registers, per-iter scale via LDS broadcast.
// PV: wave w owns c-strip [128w,128w+128); skip acc rescale when scale==1.
__global__ __launch_bounds__(256) void k_attn(
    const unsigned short* __restrict__ qhi, const unsigned short* __restrict__ qlo,
    const unsigned short* __restrict__ khi, const unsigned short* __restrict__ klo,
    const unsigned short* __restrict__ vbf, const float* __restrict__ x,
    const float* __restrict__ gamma, float* __restrict__ out) {
  __shared__ float S_lds[32][132];           // [i][j] f32, throughput-minimal banks
  __shared__ unsigned short P_lds[32][136];  // [i][j] bf16
  __shared__ float scale_lds[32];
  __shared__ float sfin_lds[32];
  const int b = blockIdx.x & 7;              // batch-pinned XCD swizzle
  const int i0 = (blockIdx.x >> 3) * 32;
  const int t = threadIdx.x, w = t >> 6, l = t & 63, lr = l & 15, g = l >> 4;
  const int if_ = w >> 1, jf0 = (w & 1) * 4;
  const int srow = w * 8 + (l & 7), sgrp = l >> 3;  // softmax ownership

  // hoist this wave's Q B-fragments (i = i0 + if_*16 + lr)
  bf16x8 qhF[2], qlF[2];
  {
    const int i = i0 + if_ * 16 + lr;
#pragma unroll
    for (int ks = 0; ks < 2; ks++) {
      const size_t off = ((size_t)b * NN + i) * MM + ks * 32 + g * 8;
      qhF[ks] = *reinterpret_cast<const bf16x8*>(qhi + off);
      qlF[ks] = *reinterpret_cast<const bf16x8*>(qlo + off);
    }
  }

  f32x4 acc[8][2];
#pragma unroll
  for (int cf = 0; cf < 8; cf++) {
    acc[cf][0] = f32x4{0.f, 0.f, 0.f, 0.f};
    acc[cf][1] = f32x4{0.f, 0.f, 0.f, 0.f};
  }
  float m_run = -1e30f, s_run = 0.f;

  for (int jb = 0; jb < NN; jb += 128) {
    // ---- QK: S^T fragments, 3-term hi/lo split
#pragma unroll
    for (int jj = 0; jj < 4; jj++) {
      const int j = jb + (jf0 + jj) * 16 + lr;
      f32x4 sa = f32x4{0.f, 0.f, 0.f, 0.f};
#pragma unroll
      for (int ks = 0; ks < 2; ks++) {
        const size_t off = ((size_t)b * NN + j) * MM + ks * 32 + g * 8;
        const bf16x8 kh = *reinterpret_cast<const bf16x8*>(khi + off);
        const bf16x8 kl = *reinterpret_cast<const bf16x8*>(klo + off);
        sa = __builtin_amdgcn_mfma_f32_16x16x32_bf16(kh, qhF[ks], sa, 0, 0, 0);
        sa = __builtin_amdgcn_mfma_f32_16x16x32_bf16(kh, qlF[ks], sa, 0, 0, 0);
        sa = __builtin_amdgcn_mfma_f32_16x16x32_bf16(kl, qhF[ks], sa, 0, 0, 0);
      }
      // D layout: col i = lr, row j = g*4 + r
      *reinterpret_cast<f32x4*>(&S_lds[if_ * 16 + lr][(jf0 + jj) * 16 + g * 4]) = sa;
    }
    __syncthreads();

    // ---- softmax: wave w owns rows [8w, 8w+8); lane -> 16 entries of one row
    {
      f32x4 sv[4];
#pragma unroll
      for (int q = 0; q < 4; q++)
        sv[q] = *reinterpret_cast<const f32x4*>(&S_lds[srow][sgrp * 16 + q * 4]);
      float tm = -1e30f;
#pragma unroll
      for (int q = 0; q < 4; q++)
        tm = fmaxf(tm, fmaxf(fmaxf(sv[q][0], sv[q][1]), fmaxf(sv[q][2], sv[q][3])));
      tm = fmaxf(tm, __shfl_xor(tm, 8));
      tm = fmaxf(tm, __shfl_xor(tm, 16));
      tm = fmaxf(tm, __shfl_xor(tm, 32));
      const float mn = fmaxf(m_run, tm);
      const float sc = __expf(m_run - mn);
      m_run = mn;
      float p[16];
      float ps = 0.f;
#pragma unroll
      for (int q = 0; q < 4; q++) {
#pragma unroll
        for (int e = 0; e < 4; e++) {
          p[q * 4 + e] = __expf(sv[q][e] - mn);
          ps += p[q * 4 + e];
        }
      }
      ps += __shfl_xor(ps, 8);
      ps += __shfl_xor(ps, 16);
      ps += __shfl_xor(ps, 32);
      s_run = s_run * sc + ps;
      bf16x8 p0, p1;
#pragma unroll
      for (int e = 0; e < 8; e++) {
        p0[e] = (short)f2bf(p[e]);
        p1[e] = (short)f2bf(p[e + 8]);
      }
      *reinterpret_cast<bf16x8*>(&P_lds[srow][sgrp * 16]) = p0;
      *reinterpret_cast<bf16x8*>(&P_lds[srow][sgrp * 16 + 8]) = p1;
      if (sgrp == 0) scale_lds[srow] = sc;
    }
    __syncthreads();

    // ---- rescale O only if some running max moved, then PV accumulate
    {
      const float sc0 = scale_lds[lr], sc1 = scale_lds[16 + lr];
      if (__any((sc0 != 1.f) || (sc1 != 1.f))) {
#pragma unroll
        for (int cf = 0; cf < 8; cf++) {
          acc[cf][0] *= sc0;
          acc[cf][1] *= sc1;
        }
      }
    }
#pragma unroll
    for (int ks = 0; ks < 4; ks++) {
      const bf16x8 pf0 = *reinterpret_cast<const bf16x8*>(&P_lds[lr][ks * 32 + g * 8]);
      const bf16x8 pf1 = *reinterpret_cast<const bf16x8*>(&P_lds[16 + lr][ks * 32 + g * 8]);
      const size_t vcol = (size_t)jb + ks * 32 + g * 8;
#pragma unroll
      for (int cf = 0; cf < 8; cf++) {
        const int c = w * 128 + cf * 16 + lr;
        const bf16x8 vf = *reinterpret_cast<const bf16x8*>(
            vbf + ((size_t)b * CC + c) * NN + vcol);
        acc[cf][0] = __builtin_amdgcn_mfma_f32_16x16x32_bf16(vf, pf0, acc[cf][0], 0, 0, 0);
        acc[cf][1] = __builtin_amdgcn_mfma_f32_16x16x32_bf16(vf, pf1, acc[cf][1], 0, 0, 0);
      }
    }
  }

  // ---- epilogue: out = gamma * O/s + x
  if (sgrp == 0) sfin_lds[srow] = s_run;
  __syncthreads();
  const float gm = gamma[0];
  const float inv0 = gm / sfin_lds[lr], inv1 = gm / sfin_lds[16 + lr];
#pragma unroll
  for (int cf = 0; cf < 8; cf++) {
#pragma unroll
    for (int r = 0; r < 4; r++) {
      const int c = w * 128 + cf * 16 + g * 4 + r;
      const size_t rowo = ((size_t)b * CC + c) * NN;
      const int ia = i0 + lr;
      const int ib2 = i0 + 16 + lr;
      out[rowo + ia] = acc[cf][0][r] * inv0 + x[rowo + ia];
      out[rowo + ib2] = acc[cf][1][r] * inv1 + x[rowo + ib2];
    }
  }
}

extern "C" void kernel_launch(void* const* d_in, const int* in_sizes, int n_in,
                              void* d_out, int out_size, void* d_ws, size_t ws_size,
                              hipStream_t stream) {
  const float* x = (const float*)d_in[0];
  const float* wq = (const float*)d_in[1];
  const float* bq = (const float*)d_in[2];
  const float* wk = (const float*)d_in[3];
  const float* bk = (const float*)d_in[4];
  const float* wv = (const float*)d_in[5];
  const float* bv = (const float*)d_in[6];
  const float* gamma = (const float*)d_in[7];
  float* out = (float*)d_out;

  char* ws = (char*)d_ws;
  unsigned short* xT = (unsigned short*)(ws);               // 32 MB  [B][N][C] bf16
  unsigned short* vbf = (unsigned short*)(ws + 33554432);   // 32 MB  [B][C][N] bf16
  unsigned short* qhi = (unsigned short*)(ws + 67108864);   // 4 MB   [B][N][64] bf16
  unsigned short* qlo = (unsigned short*)(ws + 71303168);   // 4 MB
  unsigned short* khi = (unsigned short*)(ws + 75497472);   // 4 MB
  unsigned short* klo = (unsigned short*)(ws + 79691776);   // 4 MB

  k_transpose<<<dim3(64, 8, 8), 256, 0, stream>>>(x, xT);
  k_qkproj<<<dim3(64, 8), 256, 0, stream>>>(x, wq, bq, wk, bk, qhi, qlo, khi, klo);
  k_vproj<<<dim3(32, 8, 8), 256, 0, stream>>>(xT, wv, bv, vbf);
  k_attn<<<dim3(1024), 256, 0, stream>>>(qhi, qlo, khi, klo, vbf, x, gamma, out);
}